// Round 1
// 1217.552 us; speedup vs baseline: 1.1908x; 1.1908x over previous
//
#include <hip/hip_runtime.h>
#include <hip/hip_bf16.h>
#include <cmath>

#define TSTEPS 128
#define NENVS  64
#define HID    1024
#define G3     3072
#define MROWS  8192   // T*N

typedef unsigned short u16;
typedef unsigned long long u64;
typedef short bf8 __attribute__((ext_vector_type(8)));   // 8 bf16 = 4 VGPRs
typedef float f4  __attribute__((ext_vector_type(4)));   // MFMA acc
typedef u16  us4  __attribute__((ext_vector_type(4)));

#define FLAG_STRIDE 32   // u32s between flags (128 B) — no same-line RMW collisions

static __device__ inline u16 f2bf(float f) {
  __hip_bfloat16 h = __float2bfloat16(f);   // RNE
  return *reinterpret_cast<u16*>(&h);
}
static __device__ inline float bf2f(u16 v) {
  __hip_bfloat16 h = *reinterpret_cast<__hip_bfloat16*>(&v);
  return __bfloat162float(h);
}

// async global->LDS, 16B per lane; LDS dest = wave-uniform base + lane*16
static __device__ inline void gload16(const u16* g, u16* l) {
  __builtin_amdgcn_global_load_lds(
      (const __attribute__((address_space(1))) void*)g,
      (__attribute__((address_space(3))) void*)l, 16, 0, 0);
}

// ---------------------------------------------------------------------------
// fp32 -> bf16 cast, 4 elements/thread
__global__ __launch_bounds__(256) void k_cast4(const float4* __restrict__ src,
                                               us4* __restrict__ dst, int n4) {
  int i = blockIdx.x * 256 + threadIdx.x;
  if (i < n4) {
    float4 v = src[i];
    us4 o = { f2bf(v.x), f2bf(v.y), f2bf(v.z), f2bf(v.w) };
    dst[i] = o;
  }
}

// zero the flag array (8192 u32 = 32 KB)
__global__ __launch_bounds__(256) void k_zerofl(unsigned* __restrict__ p) {
  p[blockIdx.x * 256 + threadIdx.x] = 0u;
}

// out_tail[n][k] = float(featb_last[n][k])
__global__ __launch_bounds__(256) void k_tail(const u16* __restrict__ featb,
                                              float* __restrict__ dst) {
  __builtin_amdgcn_fence(__ATOMIC_ACQUIRE, "agent");   // defensive: kill stale lines
  int i = blockIdx.x * 256 + threadIdx.x;   // 0..65535
  dst[i] = bf2f(featb[(size_t)(TSTEPS - 1) * NENVS * HID + i]);
}

// ---------------------------------------------------------------------------
// m97-structure bf16 MFMA GEMM: C[M][N] = A[M][1024] . B[N][1024]^T + bias (+relu)
// 128x128 tile/block, BK=32, 4 waves in 2x2 (wave sub-tile 64x64, 4x4 frags).
// LDS staging via global_load_lds width=16 (4 calls/thread/K-step), single
// buffer, 2 barriers per K-step; 8 ds_read_b128 + 16 MFMA per wave per K-step.
// No LDS swizzle: T2 measured-null on 128^2 + 2-phase structure.
// CT = float (fp32 out) or u16 (bf16 out).
template<typename CT, int BIAS_PER_N, int RELU>
__global__ __launch_bounds__(256, 2) void k_gemm_bf16(const u16* __restrict__ A,
                                                      const u16* __restrict__ B,
                                                      const float* __restrict__ bias,
                                                      CT* __restrict__ C, int ldc) {
  __builtin_amdgcn_fence(__ATOMIC_ACQUIRE, "agent");   // defensive (cheap, once)
  __shared__ u16 ldsA[128 * 32];    // [row 128][k 32], 8 KB
  __shared__ u16 ldsB[128 * 32];
  const int t = threadIdx.x, wave = t >> 6, lane = t & 63;
  const int quad = lane >> 4, l16 = lane & 15;
  const int wm = wave >> 1, wn = wave & 1;       // 2x2 wave grid
  const int m0 = blockIdx.y * 128;
  const int n0 = blockIdx.x * 128;

  // --- staging identity: chunk c = 16B = 8 u16; tile = 512 chunks = [row=c>>2][k8=c&3]
  // wave w stages chunks w*128 + {0..127} via two calls (base lane-chunk c and c+64)
  const int c   = wave * 128 + lane;
  const int row = c >> 2, k8 = c & 3;
  const u16* gA0 = A + (size_t)(m0 + row) * HID + k8 * 8;
  const u16* gA1 = gA0 + (size_t)16 * HID;       // chunk c+64 -> row+16, same k8
  const u16* gB0 = B + (size_t)(n0 + row) * HID + k8 * 8;
  const u16* gB1 = gB0 + (size_t)16 * HID;
  // wave-uniform LDS bases (u16 units); chunk c lands at u16 offset c*8
  u16* lA0 = ldsA + wave * 1024;
  u16* lA1 = lA0 + 512;
  u16* lB0 = ldsB + wave * 1024;
  u16* lB1 = lB0 + 512;

  f4 acc[4][4];
#pragma unroll
  for (int mt = 0; mt < 4; ++mt)
#pragma unroll
    for (int nt = 0; nt < 4; ++nt) acc[mt][nt] = (f4){0.f, 0.f, 0.f, 0.f};

  // per-wave ds_read offsets (u16 units): row stride 32
  const int aoff0 = (wm * 64 + l16) * 32 + quad * 8;
  const int boff0 = (wn * 64 + l16) * 32 + quad * 8;

  for (int kb = 0; kb < 32; ++kb) {
    // stage A/B k-slice [*, kb*32 .. kb*32+32)
    const int ko = kb * 32;
    gload16(gA0 + ko, lA0);
    gload16(gA1 + ko, lA1);
    gload16(gB0 + ko, lB0);
    gload16(gB1 + ko, lB1);
    __syncthreads();   // drains vmcnt(0): fills complete, visible to all waves

    bf8 af[4], bfr[4];
#pragma unroll
    for (int mt = 0; mt < 4; ++mt)
      af[mt] = *(const bf8*)(ldsA + aoff0 + mt * 16 * 32);
#pragma unroll
    for (int nt = 0; nt < 4; ++nt)
      bfr[nt] = *(const bf8*)(ldsB + boff0 + nt * 16 * 32);
#pragma unroll
    for (int mt = 0; mt < 4; ++mt)
#pragma unroll
      for (int nt = 0; nt < 4; ++nt)
        acc[mt][nt] = __builtin_amdgcn_mfma_f32_16x16x32_bf16(
            af[mt], bfr[nt], acc[mt][nt], 0, 0, 0);
    __syncthreads();   // compute done before next-iteration overwrite
  }

#pragma unroll
  for (int mt = 0; mt < 4; ++mt)
#pragma unroll
    for (int nt = 0; nt < 4; ++nt) {
      const int n = n0 + wn * 64 + nt * 16 + l16;
      const float bn = BIAS_PER_N ? bias[n] : 0.f;
#pragma unroll
      for (int r = 0; r < 4; ++r) {
        const int m = m0 + wm * 64 + mt * 16 + quad * 4 + r;
        float v = acc[mt][nt][r] + (BIAS_PER_N ? bn : bias[m]);
        if (RELU) v = fmaxf(v, 0.f);
        if constexpr (sizeof(CT) == 2)
          C[(size_t)m * ldc + n] = (CT)f2bf(v);
        else
          C[(size_t)m * ldc + n] = v;
      }
    }
}

// ---------------------------------------------------------------------------
// MFMA GRU scan, team-partitioned (envs are independent in the recurrence):
//  4 teams x 64 blocks; team tm owns envs tm*16..tm*16+15; block = 16 envs x
//  16 j (wave = 4 j). Team-local barrier via per-block flags 128 B apart:
//  arrival = returning agent atomic swap; detection = per-thread agent atomic
//  load (threads t<64 only; one poller per teammate flag) + __syncthreads_and.
__global__ __launch_bounds__(256, 1) void k_gru_mfma(
    const u16*  __restrict__ giTb,          // [3072][8192] bf16
    const float* __restrict__ done,         // [8192]
    const float* __restrict__ Whh,          // [3072][1024]
    const float* __restrict__ bhh,          // [3072]
    const float* __restrict__ hxs,          // [64][1024] fp32
    const u16*  __restrict__ hb0,           // [64][1024] bf16 h0
    u16*        __restrict__ featb,         // [8192][1024] bf16, PRISTINE region
    unsigned*   __restrict__ flags) {       // [256*FLAG_STRIDE] u32, zeroed
  __builtin_amdgcn_fence(__ATOMIC_ACQUIRE, "agent");   // once: drop stale lines
  __shared__ float Ls[4][16][17];
  __shared__ u16 Lh[4][16][4];              // per-wave h gather for 8B publish
  const int t    = threadIdx.x;
  const int wave = t >> 6, lane = t & 63;
  const int quad = lane >> 4, l16 = lane & 15;
  const int b    = blockIdx.x;
  const int tm   = b & 3;                   // team 0..3
  const int jblk = b >> 2;                  // 0..63 within team
  const int j0   = jblk * 16;               // block's 16 hidden units
  const int jw   = j0 + wave * 4;           // wave's 4 hidden units
  const int env0 = tm * 16;                 // team's 16 envs

  // thread identity: env = env0 + l16, hidden unit j = jw + quad
  const int j = jw + quad;
  const int envg = env0 + l16;
  const float br = bhh[j], bz = bhh[HID + j], bn = bhh[2 * HID + j];
  const u16* giR = giTb + (size_t)j * MROWS;
  const u16* giZ = giTb + (size_t)(HID + j) * MROWS;
  const u16* giN = giTb + (size_t)(2 * HID + j) * MROWS;
  float hp = hxs[(size_t)envg * HID + j];   // register-carried h_prev[env][j]

  unsigned* myflag   = flags + (size_t)b * FLAG_STRIDE;
  unsigned* pollflag = flags + (size_t)(((t & 63) << 2) | tm) * FLAG_STRIDE; // team member (t&63)

  // --- w_hh fragments -> registers (bf16), once. N-cols: gate*4 + jj of jw..jw+3
  bf8 Bfrag[32];
  {
    const int c = l16;                      // c<12: gate=c>>2, jj=c&3; else pad
    const int gate = c >> 2, jj = c & 3;
    const float* wrow = Whh + (size_t)(HID * gate + jw + jj) * HID;
#pragma unroll
    for (int kk = 0; kk < 32; ++kk) {
      bf8 bv = {0, 0, 0, 0, 0, 0, 0, 0};
      if (c < 12) {
        const float* s = wrow + kk * 32 + quad * 8;
#pragma unroll
        for (int e = 0; e < 8; ++e) bv[e] = (short)f2bf(s[e]);
      }
      Bfrag[kk] = bv;
    }
  }

  // prefetched gi/done for step 0
  u16 girv = giR[envg], gizv = giZ[envg], ginv = giN[envg];
  float dnv = done[envg];

  for (int step = 0; step < TSTEPS; ++step) {
    const u16* hsrc = step ? (featb + (size_t)(step - 1) * (NENVS * HID)) : hb0;
    const bf8* Arow = (const bf8*)(hsrc + (size_t)envg * HID) + quad;

    // 32 plain cached A-frag loads (pristine lines -> miss -> fill via MALL)
    bf8 ar[32];
#pragma unroll
    for (int kk = 0; kk < 32; ++kk) ar[kk] = Arow[kk * 4];

    const float ir  = bf2f(girv);
    const float iz  = bf2f(gizv);
    const float in_ = bf2f(ginv);
    const float dn  = dnv;

    f4 acc0 = {0.f, 0.f, 0.f, 0.f};
    f4 acc1 = {0.f, 0.f, 0.f, 0.f};
#pragma unroll
    for (int kk = 0; kk < 32; kk += 2) {
      acc0 = __builtin_amdgcn_mfma_f32_16x16x32_bf16(ar[kk],     Bfrag[kk],     acc0, 0, 0, 0);
      acc1 = __builtin_amdgcn_mfma_f32_16x16x32_bf16(ar[kk + 1], Bfrag[kk + 1], acc1, 0, 0, 0);
    }
    const f4 acc = acc0 + acc1;

    // C-frag (row=env=quad*4+r, col=gatecol=l16) -> LDS (same-wave exchange)
    float* L = &Ls[wave][0][0];
#pragma unroll
    for (int r = 0; r < 4; ++r) L[(quad * 4 + r) * 17 + l16] = acc[r];
    const float m  = 1.0f - dn;
    const float rr = L[l16 * 17 + quad];
    const float zz = L[l16 * 17 + 4 + quad];
    const float nn = L[l16 * 17 + 8 + quad];
    const float hr = m * rr + br;            // dot(m*h,w) == m*dot(h,w)
    const float hz = m * zz + bz;
    const float hn = m * nn + bn;
    const float rg = 1.f / (1.f + __expf(-(ir + hr)));
    const float zg = 1.f / (1.f + __expf(-(iz + hz)));
    const float ng = tanhf(in_ + rg * hn);
    const float hnew = (1.f - zg) * ng + zg * (m * hp);
    hp = hnew;

    // prefetch next step's gi/done (drains under the same vmcnt(0) as h swaps)
    if (step + 1 < TSTEPS) {
      const int c2 = (step + 1) * 64 + envg;
      girv = giR[c2]; gizv = giZ[c2]; ginv = giN[c2]; dnv = done[c2];
    }

    // --- publish h at the MALL via returning atomic swap (8B/env/wave) ---
    Lh[wave][l16][quad] = f2bf(hnew);
    __builtin_amdgcn_wave_barrier();
    if (quad == 0) {
      const u64 hv = *(const u64*)&Lh[wave][l16][0];
      u64* dst = (u64*)(featb + (size_t)(step * 64 + env0 + l16) * HID + jw);
      u64 old = __hip_atomic_exchange(dst, hv, __ATOMIC_RELAXED, __HIP_MEMORY_SCOPE_AGENT);
      asm volatile("" :: "v"(old));          // keep returning form: ack = at MALL
    }

    if (step != TSTEPS - 1) {
      asm volatile("s_waitcnt vmcnt(0)" ::: "memory");   // h swaps done at MALL
      __syncthreads();                                   // all waves drained
      if (t == 0) {
        unsigned old = __hip_atomic_exchange(myflag, (unsigned)(step + 1),
                                             __ATOMIC_RELAXED, __HIP_MEMORY_SCOPE_AGENT);
        asm volatile("" :: "v"(old));
      }
      const unsigned tgt = (unsigned)(step + 1);
      int ok;
      do {
        int mine = 1;
        if (t < 64) {
          unsigned v = __hip_atomic_load(pollflag, __ATOMIC_RELAXED, __HIP_MEMORY_SCOPE_AGENT);
          mine = (int)(v >= tgt);
        }
        ok = __syncthreads_and(mine);
      } while (!ok);
      asm volatile("" ::: "memory");         // no hoisting above the barrier
    }
  }
}

// ---------------------------------------------------------------------------
extern "C" void kernel_launch(void* const* d_in, const int* in_sizes, int n_in,
                              void* d_out, int out_size, void* d_ws, size_t ws_size,
                              hipStream_t stream) {
  (void)in_sizes; (void)n_in; (void)out_size; (void)ws_size;
  const float* x     = (const float*)d_in[0];   // [8192][1024]
  const float* hxs   = (const float*)d_in[1];   // [64][1024]
  const float* done  = (const float*)d_in[2];   // [8192]
  const float* w_ih  = (const float*)d_in[3];   // [3072][1024]
  const float* w_hh  = (const float*)d_in[4];   // [3072][1024]
  const float* b_ih  = (const float*)d_in[5];   // [3072]
  const float* b_hh  = (const float*)d_in[6];   // [3072]
  const float* w_out = (const float*)d_in[7];   // [1024][1024]
  const float* b_out = (const float*)d_in[8];   // [1024]
  float* out = (float*)d_out;                   // [8192][1024] ++ [64][1024]

  // ws layout (~92.5 MB): giTb | xb | featb (PRISTINE) | wihb | woutb | hb0 | flags
  u16* giTb  = (u16*)d_ws;                               // [3072][8192] bf16
  u16* xb    = giTb + (size_t)G3 * MROWS;                // [8192][1024] bf16
  u16* featb = xb + (size_t)MROWS * HID;                 // [8192][1024] bf16
  u16* wihb  = featb + (size_t)MROWS * HID;
  u16* woutb = wihb + (size_t)G3 * HID;
  u16* hb0   = woutb + (size_t)HID * HID;
  unsigned* flags = (unsigned*)(hb0 + (size_t)NENVS * HID);  // 256*32 u32

  // casts + flag init
  k_cast4<<<dim3(MROWS * HID / 4 / 256), dim3(256), 0, stream>>>((const float4*)x, (us4*)xb, MROWS * HID / 4);
  k_cast4<<<dim3(G3 * HID / 4 / 256), dim3(256), 0, stream>>>((const float4*)w_ih, (us4*)wihb, G3 * HID / 4);
  k_cast4<<<dim3(HID * HID / 4 / 256), dim3(256), 0, stream>>>((const float4*)w_out, (us4*)woutb, HID * HID / 4);
  k_cast4<<<dim3(NENVS * HID / 4 / 256), dim3(256), 0, stream>>>((const float4*)hxs, (us4*)hb0, NENVS * HID / 4);
  k_zerofl<<<dim3(256 * FLAG_STRIDE / 256), dim3(256), 0, stream>>>(flags);

  // gi = w_ih . x^T + b_ih  -> [3072][8192] bf16
  k_gemm_bf16<u16, 0, 0><<<dim3(MROWS / 128, G3 / 128), dim3(256), 0, stream>>>(
      wihb, xb, b_ih, giTb, MROWS);

  // GRU scan (cooperative for co-residency; sync is team-local flag barrier)
  {
    const u16* giTb_c = giTb; const float* done_c = done; const float* whh_c = w_hh;
    const float* bhh_c = b_hh; const float* hxs_c = hxs;
    const u16* hb0_c = hb0; u16* featb_p = featb; unsigned* flags_p = flags;
    void* args[8] = { (void*)&giTb_c, (void*)&done_c, (void*)&whh_c, (void*)&bhh_c,
                      (void*)&hxs_c, (void*)&hb0_c, (void*)&featb_p, (void*)&flags_p };
    hipLaunchCooperativeKernel(reinterpret_cast<void*>(k_gru_mfma),
                               dim3(256), dim3(256), args, 0, stream);
  }

  // out = relu(feat . w_out^T + b_out) -> [8192][1024] fp32
  k_gemm_bf16<float, 1, 1><<<dim3(HID / 128, MROWS / 128), dim3(256), 0, stream>>>(
      featb, woutb, b_out, out, HID);

  // h_last tail
  k_tail<<<dim3(256), dim3(256), 0, stream>>>(featb, out + (size_t)MROWS * HID);
}

// Round 3
// 1192.539 us; speedup vs baseline: 1.2158x; 1.0210x over previous
//
#include <hip/hip_runtime.h>
#include <hip/hip_bf16.h>
#include <cmath>

#define TSTEPS 128
#define NENVS  64
#define HID    1024
#define G3     3072
#define MROWS  8192   // T*N

typedef unsigned short u16;
typedef unsigned long long u64;
typedef short bf8 __attribute__((ext_vector_type(8)));   // 8 bf16 = 4 VGPRs
typedef float f4  __attribute__((ext_vector_type(4)));   // MFMA acc
typedef u16  us4  __attribute__((ext_vector_type(4)));

#define FLAG_STRIDE 32   // u32s between flags (128 B) — no same-line RMW collisions

static __device__ inline u16 f2bf(float f) {
  __hip_bfloat16 h = __float2bfloat16(f);   // RNE
  return *reinterpret_cast<u16*>(&h);
}
static __device__ inline float bf2f(u16 v) {
  __hip_bfloat16 h = *reinterpret_cast<__hip_bfloat16*>(&v);
  return __bfloat162float(h);
}

// async global->LDS, 16B per lane; LDS dest = wave-uniform base + lane*16
static __device__ inline void gload16(const u16* g, u16* l) {
  __builtin_amdgcn_global_load_lds(
      (const __attribute__((address_space(1))) void*)g,
      (__attribute__((address_space(3))) void*)l, 16, 0, 0);
}

// ---------------------------------------------------------------------------
// fp32 -> bf16 cast, 4 elements/thread
__global__ __launch_bounds__(256) void k_cast4(const float4* __restrict__ src,
                                               us4* __restrict__ dst, int n4) {
  int i = blockIdx.x * 256 + threadIdx.x;
  if (i < n4) {
    float4 v = src[i];
    us4 o = { f2bf(v.x), f2bf(v.y), f2bf(v.z), f2bf(v.w) };
    dst[i] = o;
  }
}

// zero the flag array (8192 u32 = 32 KB); runtime's end-of-kernel writeback
// makes the zeros MALL/DRAM-visible before the scan.
__global__ __launch_bounds__(256) void k_zerofl(unsigned* __restrict__ p) {
  p[blockIdx.x * 256 + threadIdx.x] = 0u;
}

// out_tail[n][k] = float(featb_last[n][k])
__global__ __launch_bounds__(256) void k_tail(const u16* __restrict__ featb,
                                              float* __restrict__ dst) {
  __builtin_amdgcn_fence(__ATOMIC_ACQUIRE, "agent");   // defensive: kill stale lines
  int i = blockIdx.x * 256 + threadIdx.x;   // 0..65535
  dst[i] = bf2f(featb[(size_t)(TSTEPS - 1) * NENVS * HID + i]);
}

// ---------------------------------------------------------------------------
// bf16 MFMA GEMM: C[M][N] = A[M][1024] . B[N][1024]^T + bias (+relu)
// 128x128 tile/block, BK=32, 4 waves in 2x2. T3-minimum 2-phase: double-
// buffered LDS, STAGE(next) issued before ds_read(cur)+MFMA, ONE barrier per
// K-step (its implied vmcnt(0) drains the in-flight global_load_lds).
// SWZ: bijective XCD-chunk swizzle (requires nwg % 8 == 0).
template<typename CT, int BIAS_PER_N, int RELU, int SWZ>
__global__ __launch_bounds__(256, 2) void k_gemm_bf16(const u16* __restrict__ A,
                                                      const u16* __restrict__ B,
                                                      const float* __restrict__ bias,
                                                      CT* __restrict__ C, int ldc) {
  __builtin_amdgcn_fence(__ATOMIC_ACQUIRE, "agent");   // defensive (cheap, once)
  __shared__ u16 ldsA[2][128 * 32];    // [buf][row 128][k 32], 2 x 8 KB
  __shared__ u16 ldsB[2][128 * 32];
  const int t = threadIdx.x, wave = t >> 6, lane = t & 63;
  const int quad = lane >> 4, l16 = lane & 15;
  const int wm = wave >> 1, wn = wave & 1;       // 2x2 wave grid
  int bx = blockIdx.x, by = blockIdx.y;
  if (SWZ) {
    const unsigned nwg = gridDim.x * gridDim.y;
    const unsigned L = (unsigned)by * gridDim.x + bx;
    const unsigned w = (L & 7u) * (nwg >> 3) + (L >> 3);   // XCD gets contiguous chunk
    bx = (int)(w % gridDim.x); by = (int)(w / gridDim.x);
  }
  const int m0 = by * 128;
  const int n0 = bx * 128;

  // staging identity: chunk c = 16B = 8 u16; tile = 512 chunks = [row=c>>2][k8=c&3]
  const int c   = wave * 128 + lane;
  const int row = c >> 2, k8 = c & 3;
  const u16* gA0 = A + (size_t)(m0 + row) * HID + k8 * 8;
  const u16* gA1 = gA0 + (size_t)16 * HID;       // chunk c+64 -> row+16, same k8
  const u16* gB0 = B + (size_t)(n0 + row) * HID + k8 * 8;
  const u16* gB1 = gB0 + (size_t)16 * HID;
  const int lw = wave * 1024;                    // wave-uniform LDS chunk base (u16)

  f4 acc[4][4];
#pragma unroll
  for (int mt = 0; mt < 4; ++mt)
#pragma unroll
    for (int nt = 0; nt < 4; ++nt) acc[mt][nt] = (f4){0.f, 0.f, 0.f, 0.f};

  const int aoff0 = (wm * 64 + l16) * 32 + quad * 8;
  const int boff0 = (wn * 64 + l16) * 32 + quad * 8;

  // prologue: stage tile 0 into buf 0
  gload16(gA0, &ldsA[0][lw]);
  gload16(gA1, &ldsA[0][lw + 512]);
  gload16(gB0, &ldsB[0][lw]);
  gload16(gB1, &ldsB[0][lw + 512]);
  __syncthreads();                               // vmcnt(0) drain + barrier

  int cur = 0;
  for (int kb = 0; kb < 32; ++kb) {
    if (kb < 31) {                               // stage NEXT tile into other buf
      const int ko = (kb + 1) * 32;
      const int nb = cur ^ 1;
      gload16(gA0 + ko, &ldsA[nb][lw]);
      gload16(gA1 + ko, &ldsA[nb][lw + 512]);
      gload16(gB0 + ko, &ldsB[nb][lw]);
      gload16(gB1 + ko, &ldsB[nb][lw + 512]);
    }
    bf8 af[4], bfr[4];
#pragma unroll
    for (int mt = 0; mt < 4; ++mt)
      af[mt] = *(const bf8*)(&ldsA[cur][0] + aoff0 + mt * 16 * 32);
#pragma unroll
    for (int nt = 0; nt < 4; ++nt)
      bfr[nt] = *(const bf8*)(&ldsB[cur][0] + boff0 + nt * 16 * 32);
#pragma unroll
    for (int mt = 0; mt < 4; ++mt)
#pragma unroll
      for (int nt = 0; nt < 4; ++nt)
        acc[mt][nt] = __builtin_amdgcn_mfma_f32_16x16x32_bf16(
            af[mt], bfr[nt], acc[mt][nt], 0, 0, 0);
    if (kb < 31) {
      __syncthreads();                           // drains stage of kb+1, guards buf reuse
      cur ^= 1;
    }
  }

#pragma unroll
  for (int mt = 0; mt < 4; ++mt)
#pragma unroll
    for (int nt = 0; nt < 4; ++nt) {
      const int n = n0 + wn * 64 + nt * 16 + l16;
      const float bn = BIAS_PER_N ? bias[n] : 0.f;
#pragma unroll
      for (int r = 0; r < 4; ++r) {
        const int m = m0 + wm * 64 + mt * 16 + quad * 4 + r;
        float v = acc[mt][nt][r] + (BIAS_PER_N ? bn : bias[m]);
        if (RELU) v = fmaxf(v, 0.f);
        if constexpr (sizeof(CT) == 2)
          C[(size_t)m * ldc + n] = (CT)f2bf(v);
        else
          C[(size_t)m * ldc + n] = v;
      }
    }
}

// ---------------------------------------------------------------------------
// MFMA GRU scan (R1-proven structure). 4 teams x 64 blocks; team tm owns envs
// tm*16..+15; block = 16 envs x 16 j (wave = 4 j). Team-local barrier via
// per-block flags 128 B apart: arrival = returning agent atomic swap after
// vmcnt(0)+syncthreads; detection = wave-0 spin (one lane per teammate flag)
// + single __syncthreads release (flags are monotone -> no deadlock; memory
// order preserved: flag set after h-swaps drained, reads after barrier+clobber).
__global__ __launch_bounds__(256, 1) void k_gru_mfma(
    const u16*  __restrict__ giTb,          // [3072][8192] bf16
    const float* __restrict__ done,         // [8192]
    const float* __restrict__ Whh,          // [3072][1024]
    const float* __restrict__ bhh,          // [3072]
    const float* __restrict__ hxs,          // [64][1024] fp32
    const u16*  __restrict__ hb0,           // [64][1024] bf16 h0
    u16*        __restrict__ featb,         // [8192][1024] bf16, PRISTINE region
    unsigned*   __restrict__ flags) {       // [256*FLAG_STRIDE] u32, zeroed
  __builtin_amdgcn_fence(__ATOMIC_ACQUIRE, "agent");   // once: drop stale lines
  __shared__ float Ls[4][16][17];
  __shared__ u16 Lh[4][16][4];              // per-wave h gather for 8B publish
  const int t    = threadIdx.x;
  const int wave = t >> 6, lane = t & 63;
  const int quad = lane >> 4, l16 = lane & 15;
  const int b    = blockIdx.x;
  const int tm   = b & 3;                   // team 0..3
  const int jblk = b >> 2;                  // 0..63 within team
  const int j0   = jblk * 16;               // block's 16 hidden units
  const int jw   = j0 + wave * 4;           // wave's 4 hidden units
  const int env0 = tm * 16;                 // team's 16 envs

  // thread identity: env = env0 + l16, hidden unit j = jw + quad
  const int j = jw + quad;
  const int envg = env0 + l16;
  const float br = bhh[j], bz = bhh[HID + j], bn = bhh[2 * HID + j];
  const u16* giR = giTb + (size_t)j * MROWS;
  const u16* giZ = giTb + (size_t)(HID + j) * MROWS;
  const u16* giN = giTb + (size_t)(2 * HID + j) * MROWS;
  float hp = hxs[(size_t)envg * HID + j];   // register-carried h_prev[env][j]

  unsigned* myflag   = flags + (size_t)b * FLAG_STRIDE;
  unsigned* pollflag = flags + (size_t)(((t & 63) << 2) | tm) * FLAG_STRIDE; // team member (t&63)

  // --- w_hh fragments -> registers (bf16), once. N-cols: gate*4 + jj of jw..jw+3
  bf8 Bfrag[32];
  {
    const int c = l16;                      // c<12: gate=c>>2, jj=c&3; else pad
    const int gate = c >> 2, jj = c & 3;
    const float* wrow = Whh + (size_t)(HID * gate + jw + jj) * HID;
#pragma unroll
    for (int kk = 0; kk < 32; ++kk) {
      bf8 bv = {0, 0, 0, 0, 0, 0, 0, 0};
      if (c < 12) {
        const float* s = wrow + kk * 32 + quad * 8;
#pragma unroll
        for (int e = 0; e < 8; ++e) bv[e] = (short)f2bf(s[e]);
      }
      Bfrag[kk] = bv;
    }
  }

  // prefetched gi/done for step 0
  u16 girv = giR[envg], gizv = giZ[envg], ginv = giN[envg];
  float dnv = done[envg];

  for (int step = 0; step < TSTEPS; ++step) {
    const u16* hsrc = step ? (featb + (size_t)(step - 1) * (NENVS * HID)) : hb0;
    const bf8* Arow = (const bf8*)(hsrc + (size_t)envg * HID) + quad;

    // 32 plain cached A-frag loads (pristine lines -> miss -> fill via MALL)
    bf8 ar[32];
#pragma unroll
    for (int kk = 0; kk < 32; ++kk) ar[kk] = Arow[kk * 4];

    const float ir  = bf2f(girv);
    const float iz  = bf2f(gizv);
    const float in_ = bf2f(ginv);
    const float dn  = dnv;

    f4 acc0 = {0.f, 0.f, 0.f, 0.f};
    f4 acc1 = {0.f, 0.f, 0.f, 0.f};
#pragma unroll
    for (int kk = 0; kk < 32; kk += 2) {
      acc0 = __builtin_amdgcn_mfma_f32_16x16x32_bf16(ar[kk],     Bfrag[kk],     acc0, 0, 0, 0);
      acc1 = __builtin_amdgcn_mfma_f32_16x16x32_bf16(ar[kk + 1], Bfrag[kk + 1], acc1, 0, 0, 0);
    }
    const f4 acc = acc0 + acc1;

    // C-frag (row=env=quad*4+r, col=gatecol=l16) -> LDS (same-wave exchange)
    float* L = &Ls[wave][0][0];
#pragma unroll
    for (int r = 0; r < 4; ++r) L[(quad * 4 + r) * 17 + l16] = acc[r];
    const float m  = 1.0f - dn;
    const float rr = L[l16 * 17 + quad];
    const float zz = L[l16 * 17 + 4 + quad];
    const float nn = L[l16 * 17 + 8 + quad];
    const float hr = m * rr + br;            // dot(m*h,w) == m*dot(h,w)
    const float hz = m * zz + bz;
    const float hn = m * nn + bn;
    const float rg = 1.f / (1.f + __expf(-(ir + hr)));
    const float zg = 1.f / (1.f + __expf(-(iz + hz)));
    const float ng = tanhf(in_ + rg * hn);
    const float hnew = (1.f - zg) * ng + zg * (m * hp);
    hp = hnew;

    // prefetch next step's gi/done (drains under the same vmcnt(0) as h swaps)
    if (step + 1 < TSTEPS) {
      const int c2 = (step + 1) * 64 + envg;
      girv = giR[c2]; gizv = giZ[c2]; ginv = giN[c2]; dnv = done[c2];
    }

    // --- publish h at the MALL via returning atomic swap (8B/env/wave) ---
    Lh[wave][l16][quad] = f2bf(hnew);
    __builtin_amdgcn_wave_barrier();
    if (quad == 0) {
      const u64 hv = *(const u64*)&Lh[wave][l16][0];
      u64* dst = (u64*)(featb + (size_t)(step * 64 + env0 + l16) * HID + jw);
      u64 old = __hip_atomic_exchange(dst, hv, __ATOMIC_RELAXED, __HIP_MEMORY_SCOPE_AGENT);
      asm volatile("" :: "v"(old));          // keep returning form: ack = at MALL
    }

    if (step != TSTEPS - 1) {
      asm volatile("s_waitcnt vmcnt(0)" ::: "memory");   // h swaps done at MALL
      __syncthreads();                                   // all waves drained
      if (t == 0) {
        unsigned old = __hip_atomic_exchange(myflag, (unsigned)(step + 1),
                                             __ATOMIC_RELAXED, __HIP_MEMORY_SCOPE_AGENT);
        asm volatile("" :: "v"(old));
      }
      const unsigned tgt = (unsigned)(step + 1);
      if (t < 64) {                                      // wave 0: one lane per teammate
        while (__hip_atomic_load(pollflag, __ATOMIC_RELAXED,
                                 __HIP_MEMORY_SCOPE_AGENT) < tgt) { }
      }
      __syncthreads();                                   // release waves 1..3
      asm volatile("" ::: "memory");         // no hoisting above the barrier
    }
  }
}

// ---------------------------------------------------------------------------
extern "C" void kernel_launch(void* const* d_in, const int* in_sizes, int n_in,
                              void* d_out, int out_size, void* d_ws, size_t ws_size,
                              hipStream_t stream) {
  (void)in_sizes; (void)n_in; (void)out_size; (void)ws_size;
  const float* x     = (const float*)d_in[0];   // [8192][1024]
  const float* hxs   = (const float*)d_in[1];   // [64][1024]
  const float* done  = (const float*)d_in[2];   // [8192]
  const float* w_ih  = (const float*)d_in[3];   // [3072][1024]
  const float* w_hh  = (const float*)d_in[4];   // [3072][1024]
  const float* b_ih  = (const float*)d_in[5];   // [3072]
  const float* b_hh  = (const float*)d_in[6];   // [3072]
  const float* w_out = (const float*)d_in[7];   // [1024][1024]
  const float* b_out = (const float*)d_in[8];   // [1024]
  float* out = (float*)d_out;                   // [8192][1024] ++ [64][1024]

  // ws layout (~92.5 MB): giTb | xb | featb (PRISTINE) | wihb | woutb | hb0 | flags
  u16* giTb  = (u16*)d_ws;                               // [3072][8192] bf16
  u16* xb    = giTb + (size_t)G3 * MROWS;                // [8192][1024] bf16
  u16* featb = xb + (size_t)MROWS * HID;                 // [8192][1024] bf16
  u16* wihb  = featb + (size_t)MROWS * HID;
  u16* woutb = wihb + (size_t)G3 * HID;
  u16* hb0   = woutb + (size_t)HID * HID;
  unsigned* flags = (unsigned*)(hb0 + (size_t)NENVS * HID);  // 256*32 u32

  // casts + flag init
  k_cast4<<<dim3(MROWS * HID / 4 / 256), dim3(256), 0, stream>>>((const float4*)x, (us4*)xb, MROWS * HID / 4);
  k_cast4<<<dim3(G3 * HID / 4 / 256), dim3(256), 0, stream>>>((const float4*)w_ih, (us4*)wihb, G3 * HID / 4);
  k_cast4<<<dim3(HID * HID / 4 / 256), dim3(256), 0, stream>>>((const float4*)w_out, (us4*)woutb, HID * HID / 4);
  k_cast4<<<dim3(NENVS * HID / 4 / 256), dim3(256), 0, stream>>>((const float4*)hxs, (us4*)hb0, NENVS * HID / 4);
  k_zerofl<<<dim3(256 * FLAG_STRIDE / 256), dim3(256), 0, stream>>>(flags);

  // gi = w_ih . x^T + b_ih  -> [3072][8192] bf16   (2-phase + XCD swizzle)
  k_gemm_bf16<u16, 0, 0, 1><<<dim3(MROWS / 128, G3 / 128), dim3(256), 0, stream>>>(
      wihb, xb, b_ih, giTb, MROWS);

  // GRU scan (cooperative for co-residency; sync is team-local flag barrier)
  {
    const u16* giTb_c = giTb; const float* done_c = done; const float* whh_c = w_hh;
    const float* bhh_c = b_hh; const float* hxs_c = hxs;
    const u16* hb0_c = hb0; u16* featb_p = featb; unsigned* flags_p = flags;
    void* args[8] = { (void*)&giTb_c, (void*)&done_c, (void*)&whh_c, (void*)&bhh_c,
                      (void*)&hxs_c, (void*)&hb0_c, (void*)&featb_p, (void*)&flags_p };
    hipLaunchCooperativeKernel(reinterpret_cast<void*>(k_gru_mfma),
                               dim3(256), dim3(256), args, 0, stream);
  }

  // out = relu(feat . w_out^T + b_out) -> [8192][1024] fp32  (2-phase + swizzle)
  k_gemm_bf16<float, 1, 1, 1><<<dim3(HID / 128, MROWS / 128), dim3(256), 0, stream>>>(
      featb, woutb, b_out, out, HID);

  // h_last tail
  k_tail<<<dim3(256), dim3(256), 0, stream>>>(featb, out + (size_t)MROWS * HID);
}

// Round 4
// 1191.983 us; speedup vs baseline: 1.2164x; 1.0005x over previous
//
#include <hip/hip_runtime.h>
#include <hip/hip_bf16.h>
#include <cmath>

#define TSTEPS 128
#define NENVS  64
#define HID    1024
#define G3     3072
#define MROWS  8192   // T*N

typedef unsigned short u16;
typedef unsigned long long u64;
typedef short bf8 __attribute__((ext_vector_type(8)));   // 8 bf16 = 4 VGPRs
typedef float f4  __attribute__((ext_vector_type(4)));   // MFMA acc
typedef u16  us4  __attribute__((ext_vector_type(4)));

#define FLAG_STRIDE 32   // u32s between flags (128 B) — no same-line RMW collisions

static __device__ inline u16 f2bf(float f) {
  __hip_bfloat16 h = __float2bfloat16(f);   // RNE
  return *reinterpret_cast<u16*>(&h);
}
static __device__ inline float bf2f(u16 v) {
  __hip_bfloat16 h = *reinterpret_cast<__hip_bfloat16*>(&v);
  return __bfloat162float(h);
}

// async global->LDS, 16B per lane; LDS dest = wave-uniform base + lane*16
static __device__ inline void gload16(const u16* g, u16* l) {
  __builtin_amdgcn_global_load_lds(
      (const __attribute__((address_space(1))) void*)g,
      (__attribute__((address_space(3))) void*)l, 16, 0, 0);
}

// ---------------------------------------------------------------------------
// fp32 -> bf16 cast, 4 elements/thread
__global__ __launch_bounds__(256) void k_cast4(const float4* __restrict__ src,
                                               us4* __restrict__ dst, int n4) {
  int i = blockIdx.x * 256 + threadIdx.x;
  if (i < n4) {
    float4 v = src[i];
    us4 o = { f2bf(v.x), f2bf(v.y), f2bf(v.z), f2bf(v.w) };
    dst[i] = o;
  }
}

// zero the flag array (8192 u32 = 32 KB); runtime's end-of-kernel writeback
// makes the zeros MALL/DRAM-visible before the scan.
__global__ __launch_bounds__(256) void k_zerofl(unsigned* __restrict__ p) {
  p[blockIdx.x * 256 + threadIdx.x] = 0u;
}

// out_tail[n][k] = float(featb_last[n][k])
__global__ __launch_bounds__(256) void k_tail(const u16* __restrict__ featb,
                                              float* __restrict__ dst) {
  __builtin_amdgcn_fence(__ATOMIC_ACQUIRE, "agent");   // defensive: kill stale lines
  int i = blockIdx.x * 256 + threadIdx.x;   // 0..65535
  dst[i] = bf2f(featb[(size_t)(TSTEPS - 1) * NENVS * HID + i]);
}

// ---------------------------------------------------------------------------
// bf16 MFMA GEMM: C[M][N] = A[M][1024] . B[N][1024]^T + bias (+relu)
// 128x128 tile/block, BK=32, 4 waves in 2x2. 2-phase double-buffered LDS.
// K-loop is MALL-fill-latency-bound (~600cy drain per step vs ~150cy MFMA),
// so co-residency is the lever: __launch_bounds__(256,4) = 4 blocks/CU
// (LDS 4x32KB=128<=160KB, ~116 VGPR <= 128 cap) overlapping 4 stall streams.
// SWZ: bijective XCD-chunk swizzle (requires nwg % 8 == 0).
template<typename CT, int BIAS_PER_N, int RELU, int SWZ>
__global__ __launch_bounds__(256, 4) void k_gemm_bf16(const u16* __restrict__ A,
                                                      const u16* __restrict__ B,
                                                      const float* __restrict__ bias,
                                                      CT* __restrict__ C, int ldc) {
  __builtin_amdgcn_fence(__ATOMIC_ACQUIRE, "agent");   // defensive (cheap, once)
  __shared__ u16 ldsA[2][128 * 32];    // [buf][row 128][k 32], 2 x 8 KB
  __shared__ u16 ldsB[2][128 * 32];
  const int t = threadIdx.x, wave = t >> 6, lane = t & 63;
  const int quad = lane >> 4, l16 = lane & 15;
  const int wm = wave >> 1, wn = wave & 1;       // 2x2 wave grid
  int bx = blockIdx.x, by = blockIdx.y;
  if (SWZ) {
    const unsigned nwg = gridDim.x * gridDim.y;
    const unsigned L = (unsigned)by * gridDim.x + bx;
    const unsigned w = (L & 7u) * (nwg >> 3) + (L >> 3);   // XCD gets contiguous chunk
    bx = (int)(w % gridDim.x); by = (int)(w / gridDim.x);
  }
  const int m0 = by * 128;
  const int n0 = bx * 128;

  // staging identity: chunk c = 16B = 8 u16; tile = 512 chunks = [row=c>>2][k8=c&3]
  const int c   = wave * 128 + lane;
  const int row = c >> 2, k8 = c & 3;
  const u16* gA0 = A + (size_t)(m0 + row) * HID + k8 * 8;
  const u16* gA1 = gA0 + (size_t)16 * HID;       // chunk c+64 -> row+16, same k8
  const u16* gB0 = B + (size_t)(n0 + row) * HID + k8 * 8;
  const u16* gB1 = gB0 + (size_t)16 * HID;
  const int lw = wave * 1024;                    // wave-uniform LDS chunk base (u16)

  f4 acc[4][4];
#pragma unroll
  for (int mt = 0; mt < 4; ++mt)
#pragma unroll
    for (int nt = 0; nt < 4; ++nt) acc[mt][nt] = (f4){0.f, 0.f, 0.f, 0.f};

  const int aoff0 = (wm * 64 + l16) * 32 + quad * 8;
  const int boff0 = (wn * 64 + l16) * 32 + quad * 8;

  // prologue: stage tile 0 into buf 0
  gload16(gA0, &ldsA[0][lw]);
  gload16(gA1, &ldsA[0][lw + 512]);
  gload16(gB0, &ldsB[0][lw]);
  gload16(gB1, &ldsB[0][lw + 512]);
  __syncthreads();                               // vmcnt(0) drain + barrier

  int cur = 0;
  for (int kb = 0; kb < 32; ++kb) {
    if (kb < 31) {                               // stage NEXT tile into other buf
      const int ko = (kb + 1) * 32;
      const int nb = cur ^ 1;
      gload16(gA0 + ko, &ldsA[nb][lw]);
      gload16(gA1 + ko, &ldsA[nb][lw + 512]);
      gload16(gB0 + ko, &ldsB[nb][lw]);
      gload16(gB1 + ko, &ldsB[nb][lw + 512]);
    }
    bf8 af[4], bfr[4];
#pragma unroll
    for (int mt = 0; mt < 4; ++mt)
      af[mt] = *(const bf8*)(&ldsA[cur][0] + aoff0 + mt * 16 * 32);
#pragma unroll
    for (int nt = 0; nt < 4; ++nt)
      bfr[nt] = *(const bf8*)(&ldsB[cur][0] + boff0 + nt * 16 * 32);
#pragma unroll
    for (int mt = 0; mt < 4; ++mt)
#pragma unroll
      for (int nt = 0; nt < 4; ++nt)
        acc[mt][nt] = __builtin_amdgcn_mfma_f32_16x16x32_bf16(
            af[mt], bfr[nt], acc[mt][nt], 0, 0, 0);
    if (kb < 31) {
      __syncthreads();                           // drains stage of kb+1, guards buf reuse
      cur ^= 1;
    }
  }

#pragma unroll
  for (int mt = 0; mt < 4; ++mt)
#pragma unroll
    for (int nt = 0; nt < 4; ++nt) {
      const int n = n0 + wn * 64 + nt * 16 + l16;
      const float bn = BIAS_PER_N ? bias[n] : 0.f;
#pragma unroll
      for (int r = 0; r < 4; ++r) {
        const int m = m0 + wm * 64 + mt * 16 + quad * 4 + r;
        float v = acc[mt][nt][r] + (BIAS_PER_N ? bn : bias[m]);
        if (RELU) v = fmaxf(v, 0.f);
        if constexpr (sizeof(CT) == 2)
          C[(size_t)m * ldc + n] = (CT)f2bf(v);
        else
          C[(size_t)m * ldc + n] = v;
      }
    }
}

// ---------------------------------------------------------------------------
// MFMA GRU scan (R3-proven structure). 4 teams x 64 blocks; team tm owns envs
// tm*16..+15; block = 16 envs x 16 j (wave = 4 j). Team-local barrier via
// per-block flags 128 B apart: arrival = returning agent atomic swap after
// vmcnt(0)+syncthreads; detection = wave-0 spin (one lane per teammate flag,
// s_sleep backoff to cut MALL atomic contention) + single __syncthreads
// release (flags monotone -> no deadlock; memory order preserved).
__global__ __launch_bounds__(256, 1) void k_gru_mfma(
    const u16*  __restrict__ giTb,          // [3072][8192] bf16
    const float* __restrict__ done,         // [8192]
    const float* __restrict__ Whh,          // [3072][1024]
    const float* __restrict__ bhh,          // [3072]
    const float* __restrict__ hxs,          // [64][1024] fp32
    const u16*  __restrict__ hb0,           // [64][1024] bf16 h0
    u16*        __restrict__ featb,         // [8192][1024] bf16, PRISTINE region
    unsigned*   __restrict__ flags) {       // [256*FLAG_STRIDE] u32, zeroed
  __builtin_amdgcn_fence(__ATOMIC_ACQUIRE, "agent");   // once: drop stale lines
  __shared__ float Ls[4][16][17];
  __shared__ u16 Lh[4][16][4];              // per-wave h gather for 8B publish
  const int t    = threadIdx.x;
  const int wave = t >> 6, lane = t & 63;
  const int quad = lane >> 4, l16 = lane & 15;
  const int b    = blockIdx.x;
  const int tm   = b & 3;                   // team 0..3
  const int jblk = b >> 2;                  // 0..63 within team
  const int j0   = jblk * 16;               // block's 16 hidden units
  const int jw   = j0 + wave * 4;           // wave's 4 hidden units
  const int env0 = tm * 16;                 // team's 16 envs

  // thread identity: env = env0 + l16, hidden unit j = jw + quad
  const int j = jw + quad;
  const int envg = env0 + l16;
  const float br = bhh[j], bz = bhh[HID + j], bn = bhh[2 * HID + j];
  const u16* giR = giTb + (size_t)j * MROWS;
  const u16* giZ = giTb + (size_t)(HID + j) * MROWS;
  const u16* giN = giTb + (size_t)(2 * HID + j) * MROWS;
  float hp = hxs[(size_t)envg * HID + j];   // register-carried h_prev[env][j]

  unsigned* myflag   = flags + (size_t)b * FLAG_STRIDE;
  unsigned* pollflag = flags + (size_t)(((t & 63) << 2) | tm) * FLAG_STRIDE; // team member (t&63)

  // --- w_hh fragments -> registers (bf16), once. N-cols: gate*4 + jj of jw..jw+3
  bf8 Bfrag[32];
  {
    const int c = l16;                      // c<12: gate=c>>2, jj=c&3; else pad
    const int gate = c >> 2, jj = c & 3;
    const float* wrow = Whh + (size_t)(HID * gate + jw + jj) * HID;
#pragma unroll
    for (int kk = 0; kk < 32; ++kk) {
      bf8 bv = {0, 0, 0, 0, 0, 0, 0, 0};
      if (c < 12) {
        const float* s = wrow + kk * 32 + quad * 8;
#pragma unroll
        for (int e = 0; e < 8; ++e) bv[e] = (short)f2bf(s[e]);
      }
      Bfrag[kk] = bv;
    }
  }

  // prefetched gi/done for step 0
  u16 girv = giR[envg], gizv = giZ[envg], ginv = giN[envg];
  float dnv = done[envg];

  for (int step = 0; step < TSTEPS; ++step) {
    const u16* hsrc = step ? (featb + (size_t)(step - 1) * (NENVS * HID)) : hb0;
    const bf8* Arow = (const bf8*)(hsrc + (size_t)envg * HID) + quad;

    // 32 plain cached A-frag loads (pristine lines -> miss -> fill via MALL)
    bf8 ar[32];
#pragma unroll
    for (int kk = 0; kk < 32; ++kk) ar[kk] = Arow[kk * 4];

    const float ir  = bf2f(girv);
    const float iz  = bf2f(gizv);
    const float in_ = bf2f(ginv);
    const float dn  = dnv;

    f4 acc0 = {0.f, 0.f, 0.f, 0.f};
    f4 acc1 = {0.f, 0.f, 0.f, 0.f};
#pragma unroll
    for (int kk = 0; kk < 32; kk += 2) {
      acc0 = __builtin_amdgcn_mfma_f32_16x16x32_bf16(ar[kk],     Bfrag[kk],     acc0, 0, 0, 0);
      acc1 = __builtin_amdgcn_mfma_f32_16x16x32_bf16(ar[kk + 1], Bfrag[kk + 1], acc1, 0, 0, 0);
    }
    const f4 acc = acc0 + acc1;

    // C-frag (row=env=quad*4+r, col=gatecol=l16) -> LDS (same-wave exchange)
    float* L = &Ls[wave][0][0];
#pragma unroll
    for (int r = 0; r < 4; ++r) L[(quad * 4 + r) * 17 + l16] = acc[r];
    const float m  = 1.0f - dn;
    const float rr = L[l16 * 17 + quad];
    const float zz = L[l16 * 17 + 4 + quad];
    const float nn = L[l16 * 17 + 8 + quad];
    const float hr = m * rr + br;            // dot(m*h,w) == m*dot(h,w)
    const float hz = m * zz + bz;
    const float hn = m * nn + bn;
    const float rg = 1.f / (1.f + __expf(-(ir + hr)));
    const float zg = 1.f / (1.f + __expf(-(iz + hz)));
    const float ng = tanhf(in_ + rg * hn);
    const float hnew = (1.f - zg) * ng + zg * (m * hp);
    hp = hnew;

    // prefetch next step's gi/done (drains under the same vmcnt(0) as h swaps)
    if (step + 1 < TSTEPS) {
      const int c2 = (step + 1) * 64 + envg;
      girv = giR[c2]; gizv = giZ[c2]; ginv = giN[c2]; dnv = done[c2];
    }

    // --- publish h at the MALL via returning atomic swap (8B/env/wave) ---
    Lh[wave][l16][quad] = f2bf(hnew);
    __builtin_amdgcn_wave_barrier();
    if (quad == 0) {
      const u64 hv = *(const u64*)&Lh[wave][l16][0];
      u64* dst = (u64*)(featb + (size_t)(step * 64 + env0 + l16) * HID + jw);
      u64 old = __hip_atomic_exchange(dst, hv, __ATOMIC_RELAXED, __HIP_MEMORY_SCOPE_AGENT);
      asm volatile("" :: "v"(old));          // keep returning form: ack = at MALL
    }

    if (step != TSTEPS - 1) {
      asm volatile("s_waitcnt vmcnt(0)" ::: "memory");   // h swaps done at MALL
      __syncthreads();                                   // all waves drained
      if (t == 0) {
        unsigned old = __hip_atomic_exchange(myflag, (unsigned)(step + 1),
                                             __ATOMIC_RELAXED, __HIP_MEMORY_SCOPE_AGENT);
        asm volatile("" :: "v"(old));
      }
      const unsigned tgt = (unsigned)(step + 1);
      if (t < 64) {                                      // wave 0: one lane per teammate
        while (__hip_atomic_load(pollflag, __ATOMIC_RELAXED,
                                 __HIP_MEMORY_SCOPE_AGENT) < tgt) {
          __builtin_amdgcn_s_sleep(1);                   // ~64cy backoff: cut MALL spam
        }
      }
      __syncthreads();                                   // release waves 1..3
      asm volatile("" ::: "memory");         // no hoisting above the barrier
    }
  }
}

// ---------------------------------------------------------------------------
extern "C" void kernel_launch(void* const* d_in, const int* in_sizes, int n_in,
                              void* d_out, int out_size, void* d_ws, size_t ws_size,
                              hipStream_t stream) {
  (void)in_sizes; (void)n_in; (void)out_size; (void)ws_size;
  const float* x     = (const float*)d_in[0];   // [8192][1024]
  const float* hxs   = (const float*)d_in[1];   // [64][1024]
  const float* done  = (const float*)d_in[2];   // [8192]
  const float* w_ih  = (const float*)d_in[3];   // [3072][1024]
  const float* w_hh  = (const float*)d_in[4];   // [3072][1024]
  const float* b_ih  = (const float*)d_in[5];   // [3072]
  const float* b_hh  = (const float*)d_in[6];   // [3072]
  const float* w_out = (const float*)d_in[7];   // [1024][1024]
  const float* b_out = (const float*)d_in[8];   // [1024]
  float* out = (float*)d_out;                   // [8192][1024] ++ [64][1024]

  // ws layout (~92.5 MB): giTb | xb | featb (PRISTINE) | wihb | woutb | hb0 | flags
  u16* giTb  = (u16*)d_ws;                               // [3072][8192] bf16
  u16* xb    = giTb + (size_t)G3 * MROWS;                // [8192][1024] bf16
  u16* featb = xb + (size_t)MROWS * HID;                 // [8192][1024] bf16
  u16* wihb  = featb + (size_t)MROWS * HID;
  u16* woutb = wihb + (size_t)G3 * HID;
  u16* hb0   = woutb + (size_t)HID * HID;
  unsigned* flags = (unsigned*)(hb0 + (size_t)NENVS * HID);  // 256*32 u32

  // casts + flag init
  k_cast4<<<dim3(MROWS * HID / 4 / 256), dim3(256), 0, stream>>>((const float4*)x, (us4*)xb, MROWS * HID / 4);
  k_cast4<<<dim3(G3 * HID / 4 / 256), dim3(256), 0, stream>>>((const float4*)w_ih, (us4*)wihb, G3 * HID / 4);
  k_cast4<<<dim3(HID * HID / 4 / 256), dim3(256), 0, stream>>>((const float4*)w_out, (us4*)woutb, HID * HID / 4);
  k_cast4<<<dim3(NENVS * HID / 4 / 256), dim3(256), 0, stream>>>((const float4*)hxs, (us4*)hb0, NENVS * HID / 4);
  k_zerofl<<<dim3(256 * FLAG_STRIDE / 256), dim3(256), 0, stream>>>(flags);

  // gi = w_ih . x^T + b_ih  -> [3072][8192] bf16   (2-phase + XCD swizzle)
  k_gemm_bf16<u16, 0, 0, 1><<<dim3(MROWS / 128, G3 / 128), dim3(256), 0, stream>>>(
      wihb, xb, b_ih, giTb, MROWS);

  // GRU scan (cooperative for co-residency; sync is team-local flag barrier)
  {
    const u16* giTb_c = giTb; const float* done_c = done; const float* whh_c = w_hh;
    const float* bhh_c = b_hh; const float* hxs_c = hxs;
    const u16* hb0_c = hb0; u16* featb_p = featb; unsigned* flags_p = flags;
    void* args[8] = { (void*)&giTb_c, (void*)&done_c, (void*)&whh_c, (void*)&bhh_c,
                      (void*)&hxs_c, (void*)&hb0_c, (void*)&featb_p, (void*)&flags_p };
    hipLaunchCooperativeKernel(reinterpret_cast<void*>(k_gru_mfma),
                               dim3(256), dim3(256), args, 0, stream);
  }

  // out = relu(feat . w_out^T + b_out) -> [8192][1024] fp32  (2-phase + swizzle)
  k_gemm_bf16<float, 1, 1, 1><<<dim3(HID / 128, MROWS / 128), dim3(256), 0, stream>>>(
      featb, woutb, b_out, out, HID);

  // h_last tail
  k_tail<<<dim3(256), dim3(256), 0, stream>>>(featb, out + (size_t)MROWS * HID);
}